// Round 20
// baseline (47.874 us; speedup 1.0000x reference)
//
#include <hip/hip_runtime.h>
#include <hip/hip_cooperative_groups.h>
#include <math.h>

#define B 4
#define S 4096
#define N 4096
#define BLK 1024           // 16 waves, 1 block/CU, 4 waves/SIMD
#define NW 16
#define W 2                // two 32-col B-frags -> 64 s per block
#define JTW 8              // j-tiles (32 rows) per wave = (N/32)/NW
#define INF 3.4e38f

typedef _Float16 f16x8  __attribute__((ext_vector_type(8)));
typedef float    f32x16 __attribute__((ext_vector_type(16)));

// 32x32x16 K-packed Gram MFMA (body identical to R19), full-N per block,
// no LDS staging; SINGLE cooperative launch: grid.sync() then the 4
// stile==0 blocks reduce their batch's 64 tile sums -> out[b].
// A (cloud pt j): {-y0,-y1,-y2, hy_hi, hy_lo, 0,0,0}
// B (grid s, cols=lane&31): lanes<32 {x0,x1,x2,1,1,0,0,0}; lanes>=32 zero.
// D[j][s] = hy - x.y ; u = hx + min_j D ; d = sqrt(max(2u,0)).
__global__ __launch_bounds__(BLK, 4) void sdf_mfma(
    const float* __restrict__ grid,   // [B,S,3]
    const float* __restrict__ gts,    // [B,N,3]
    const float* __restrict__ preds,  // [B,N,3]
    float* __restrict__ pb,           // [B][S/64]
    float* __restrict__ out)          // [B]
{
    __shared__ float sm[NW * 2 * 64]; // 8 KB only

    const int tid   = threadIdx.x;
    const int lane  = tid & 63;
    const int wv    = tid >> 6;       // 0..15
    const int l31   = lane & 31;
    const int stile = blockIdx.x;     // 64 tiles of 64 s
    const int b     = blockIdx.y;
    const int scol  = stile * 64;

    // ---- B-frags + hx (cols = lane&31; lanes 32-63 zero kill k=8..15) ----
    const bool lo32 = (lane < 32);
    f16x8 bf[W];
    float hx[W];
    #pragma unroll
    for (int w = 0; w < W; ++w) {
        const float* xp = grid + ((size_t)b * S + scol + w * 32 + l31) * 3;
        float x0 = (float)(_Float16)xp[0];
        float x1 = (float)(_Float16)xp[1];
        float x2 = (float)(_Float16)xp[2];
        hx[w] = 0.5f * (x0 * x0 + x1 * x1 + x2 * x2);
        f16x8 bb = { (_Float16)x0, (_Float16)x1, (_Float16)x2,
                     (_Float16)1.f, (_Float16)1.f,
                     (_Float16)0.f, (_Float16)0.f, (_Float16)0.f };
        f16x8 z  = { (_Float16)0.f, (_Float16)0.f, (_Float16)0.f, (_Float16)0.f,
                     (_Float16)0.f, (_Float16)0.f, (_Float16)0.f, (_Float16)0.f };
        bf[w] = lo32 ? bb : z;
    }

    // per-lane row base within the wave's j-slice: rows jt0 + l31
    const size_t cb = (size_t)b * N * 3;
    const float* pp = preds + cb + ((size_t)(wv * JTW * 32) + l31) * 3;
    const float* gg = gts   + cb + ((size_t)(wv * JTW * 32) + l31) * 3;

    const f32x16 zc = { 0.f, 0.f, 0.f, 0.f, 0.f, 0.f, 0.f, 0.f,
                        0.f, 0.f, 0.f, 0.f, 0.f, 0.f, 0.f, 0.f };
    float accpa = INF, accpb = INF, accga = INF, accgb = INF;

    #pragma unroll
    for (int jt = 0; jt < JTW; ++jt) {
        // ---- preds: load own row, pack, 2 MFMAs, fold ----
        {
            const float* yp = pp + (size_t)jt * 32 * 3;
            float y0 = (float)(_Float16)yp[0];
            float y1 = (float)(_Float16)yp[1];
            float y2 = (float)(_Float16)yp[2];
            float hy = 0.5f * (y0 * y0 + y1 * y1 + y2 * y2);
            _Float16 hh = (_Float16)hy;
            _Float16 hl = (_Float16)(hy - (float)hh);
            const f16x8 af = { (_Float16)(-y0), (_Float16)(-y1), (_Float16)(-y2),
                               hh, hl, (_Float16)0.f, (_Float16)0.f, (_Float16)0.f };
            #pragma unroll
            for (int w = 0; w < W; ++w) {
                f32x16 d = __builtin_amdgcn_mfma_f32_32x32x16_f16(af, bf[w], zc, 0, 0, 0);
                float a0 = (w == 0) ? accpa : accpb;
                a0 = fminf(fminf(a0, d[0]),  d[1]);
                a0 = fminf(fminf(a0, d[2]),  d[3]);
                a0 = fminf(fminf(a0, d[4]),  d[5]);
                a0 = fminf(fminf(a0, d[6]),  d[7]);
                a0 = fminf(fminf(a0, d[8]),  d[9]);
                a0 = fminf(fminf(a0, d[10]), d[11]);
                a0 = fminf(fminf(a0, d[12]), d[13]);
                a0 = fminf(fminf(a0, d[14]), d[15]);
                if (w == 0) accpa = a0; else accpb = a0;
            }
        }
        // ---- gts ----
        {
            const float* yp = gg + (size_t)jt * 32 * 3;
            float y0 = (float)(_Float16)yp[0];
            float y1 = (float)(_Float16)yp[1];
            float y2 = (float)(_Float16)yp[2];
            float hy = 0.5f * (y0 * y0 + y1 * y1 + y2 * y2);
            _Float16 hh = (_Float16)hy;
            _Float16 hl = (_Float16)(hy - (float)hh);
            const f16x8 af = { (_Float16)(-y0), (_Float16)(-y1), (_Float16)(-y2),
                               hh, hl, (_Float16)0.f, (_Float16)0.f, (_Float16)0.f };
            #pragma unroll
            for (int w = 0; w < W; ++w) {
                f32x16 d = __builtin_amdgcn_mfma_f32_32x32x16_f16(af, bf[w], zc, 0, 0, 0);
                float a0 = (w == 0) ? accga : accgb;
                a0 = fminf(fminf(a0, d[0]),  d[1]);
                a0 = fminf(fminf(a0, d[2]),  d[3]);
                a0 = fminf(fminf(a0, d[4]),  d[5]);
                a0 = fminf(fminf(a0, d[6]),  d[7]);
                a0 = fminf(fminf(a0, d[8]),  d[9]);
                a0 = fminf(fminf(a0, d[10]), d[11]);
                a0 = fminf(fminf(a0, d[12]), d[13]);
                a0 = fminf(fminf(a0, d[14]), d[15]);
                if (w == 0) accga = a0; else accgb = a0;
            }
        }
    }

    // ---- cross-lane (row halves) + cross-wave fold + block tail ----
    {
        float mp0 = fminf(accpa, __shfl_xor(accpa, 32, 64));
        float mp1 = fminf(accpb, __shfl_xor(accpb, 32, 64));
        float mg0 = fminf(accga, __shfl_xor(accga, 32, 64));
        float mg1 = fminf(accgb, __shfl_xor(accgb, 32, 64));
        if (lo32) {
            sm[(wv * 2 + 0) * 64 +  0 + l31] = hx[0] + mp0;
            sm[(wv * 2 + 0) * 64 + 32 + l31] = hx[1] + mp1;
            sm[(wv * 2 + 1) * 64 +  0 + l31] = hx[0] + mg0;
            sm[(wv * 2 + 1) * 64 + 32 + l31] = hx[1] + mg1;
        }
    }
    __syncthreads();
    if (tid < 64) {
        float mp = INF, mg = INF;
        #pragma unroll
        for (int v = 0; v < NW; ++v) {
            mp = fminf(mp, sm[(v * 2 + 0) * 64 + tid]);
            mg = fminf(mg, sm[(v * 2 + 1) * 64 + tid]);
        }
        float v = fabsf(sqrtf(fmaxf(2.f * mp, 0.f)) - sqrtf(fmaxf(2.f * mg, 0.f)));
        v += __shfl_down(v, 32, 64);
        v += __shfl_down(v, 16, 64);
        v += __shfl_down(v, 8, 64);
        v += __shfl_down(v, 4, 64);
        v += __shfl_down(v, 2, 64);
        v += __shfl_down(v, 1, 64);
        if (tid == 0) pb[b * 64 + stile] = v;
    }

    // ---- grid-wide barrier, then 4 blocks produce out[b] ----
    cooperative_groups::this_grid().sync();

    if (stile == 0 && tid < 64) {
        float v = pb[b * 64 + tid];
        v += __shfl_down(v, 32, 64);
        v += __shfl_down(v, 16, 64);
        v += __shfl_down(v, 8, 64);
        v += __shfl_down(v, 4, 64);
        v += __shfl_down(v, 2, 64);
        v += __shfl_down(v, 1, 64);
        if (tid == 0) out[b] = v / (float)S;
    }
}

extern "C" void kernel_launch(void* const* d_in, const int* in_sizes, int n_in,
                              void* d_out, int out_size, void* d_ws, size_t ws_size,
                              hipStream_t stream) {
    const float* grid_p = (const float*)d_in[0];
    const float* gts_p  = (const float*)d_in[1];
    const float* preds_p= (const float*)d_in[2];
    float* out = (float*)d_out;
    float* pb  = (float*)d_ws;        // 256 floats

    void* args[] = { (void*)&grid_p, (void*)&gts_p, (void*)&preds_p,
                     (void*)&pb, (void*)&out };
    dim3 g1(S / 64, B);               // (64, 4) = 256 blocks, 1/CU
    dim3 blk(BLK);
    hipLaunchCooperativeKernel((const void*)sdf_mfma, g1, blk, args, 0, stream);
}